// Round 14
// baseline (360.798 us; speedup 1.0000x reference)
//
#include <hip/hip_runtime.h>
#include <math.h>

#define NN 100000
#define EE 800000
#define IN_DIM 128
#define HID 32
#define HEADS 4
#define QKV 128         // HEADS*HID
#define COLS 416        // 3*QKV + HID (q|k|v|skip)
#define QBH_W 128       // q bf16 row (256 B)
#define SB_W 32         // skip fp32 row (128 B)
#define KV_W 256        // interleaved bf16: 32 groups of [k x4 | v x4] (512-B rows)
#define OUT_DIM 16
#define NTILE 26        // 416/16 col-tiles
#define NBIN 128        // dst-range bins for CSR sort
#define BINW 782        // ceil(NN/NBIN); 128*782 = 100096 >= NN
#define CH 2048         // edges per chunk
#define NCHUNK 391      // ceil(EE/CH)
// (1/sqrt(32)) * log2(e): pre-folded into q so p = exp2(part)
#define QSCALE 0.25503512f

typedef __attribute__((ext_vector_type(8))) _Float16 half8;
typedef __attribute__((ext_vector_type(4))) float floatx4;

__device__ __forceinline__ unsigned short f2bf(float f) {
    unsigned int u = __float_as_uint(f);
    unsigned int r = (u + 0x7FFF + ((u >> 16) & 1)) >> 16;   // RNE
    return (unsigned short)r;
}
__device__ __forceinline__ float bf2f(unsigned short h) {
    return __uint_as_float((unsigned int)h << 16);
}
__device__ __forceinline__ float bf_lo(unsigned int d) {
    return __uint_as_float(d << 16);
}
__device__ __forceinline__ float bf_hi(unsigned int d) {
    return __uint_as_float(d & 0xFFFF0000u);
}
__device__ __forceinline__ unsigned short f2h(float f) {
    _Float16 h = (_Float16)f;                  // v_cvt_f16_f32, RNE
    return __builtin_bit_cast(unsigned short, h);
}

// ---------------- fragment-pack BOTH layers' W (f16 single plane) + biases
// Wf[((c*26 + t)*64 + lane)*8 + j] = W[(c*32 + (lane>>4)*8 + j)][t*16 + (lane&15)]
__device__ __forceinline__ void pack_one(
        const float* __restrict__ Wq, const float* __restrict__ Wk,
        const float* __restrict__ Wv, const float* __restrict__ Ws,
        const float* __restrict__ bq, const float* __restrict__ bk,
        const float* __restrict__ bv, const float* __restrict__ bs,
        unsigned short* __restrict__ Wf, float* __restrict__ bp,
        int K, int idx) {
    if (idx < COLS) {
        float b;
        if (idx < 128)      b = bq[idx];
        else if (idx < 256) b = bk[idx - 128];
        else if (idx < 384) b = bv[idx - 256];
        else                b = bs[idx - 384];
        bp[idx] = b;
    }
    int nch = K >> 5;
    if (idx >= nch * NTILE * 64) return;
    int lane = idx & 63;
    int tt = (idx >> 6) % NTILE;
    int c = idx / (NTILE * 64);
    int k0 = c * 32 + (lane >> 4) * 8;
    int col = tt * 16 + (lane & 15);
    #pragma unroll
    for (int j = 0; j < 8; ++j) {
        int k = k0 + j;
        float w;
        if (col < 128)      w = Wq[(size_t)k * 128 + col];
        else if (col < 256) w = Wk[(size_t)k * 128 + (col - 128)];
        else if (col < 384) w = Wv[(size_t)k * 128 + (col - 256)];
        else                w = Ws[(size_t)k * 32 + (col - 384)];
        Wf[(size_t)idx * 8 + j] = f2h(w);
    }
}

__global__ void pack_frag2(
        const float* __restrict__ Wq0, const float* __restrict__ Wk0,
        const float* __restrict__ Wv0, const float* __restrict__ Ws0,
        const float* __restrict__ bq0, const float* __restrict__ bk0,
        const float* __restrict__ bv0, const float* __restrict__ bs0,
        const float* __restrict__ Wq1, const float* __restrict__ Wk1,
        const float* __restrict__ Wv1, const float* __restrict__ Ws1,
        const float* __restrict__ bq1, const float* __restrict__ bk1,
        const float* __restrict__ bv1, const float* __restrict__ bs1,
        unsigned short* __restrict__ Wf0, float* __restrict__ bp0,
        unsigned short* __restrict__ Wf1, float* __restrict__ bp1) {
    const int L0N = 4 * NTILE * 64;   // 6656
    int gid = blockIdx.x * blockDim.x + threadIdx.x;
    if (gid < L0N) {
        pack_one(Wq0, Wk0, Wv0, Ws0, bq0, bk0, bv0, bs0, Wf0, bp0, 128, gid);
    } else {
        pack_one(Wq1, Wk1, Wv1, Ws1, bq1, bk1, bv1, bs1, Wf1, bp1, 32, gid - L0N);
    }
}

// ---------------- CSR build: ATOMIC-FREE deterministic bin sort ----------
__global__ __launch_bounds__(256) void chunk_hist(
        const int* __restrict__ ei, int* __restrict__ cmat) {
    __shared__ int cnt[NBIN];
    const int t = threadIdx.x;
    const int c = blockIdx.x;
    const int c0 = c * CH;
    const int nc = min(CH, EE - c0);
    if (t < NBIN) cnt[t] = 0;
    __syncthreads();
    for (int i = t; i < nc; i += 256)
        atomicAdd(&cnt[ei[EE + c0 + i] / BINW], 1);
    __syncthreads();
    if (t < NBIN) cmat[c * NBIN + t] = cnt[t];
}

// 128 blocks (one per bin): block-scan over the 391 chunk counts ->
// omat[c][b] = LOCAL write base; btot[b] = bin total.
__global__ __launch_bounds__(256) void bin_prefix(
        const int* __restrict__ cmat, int* __restrict__ omat,
        int* __restrict__ btot) {
    __shared__ int ssum[256];
    const int b = blockIdx.x;
    const int t = threadIdx.x;
    int c0 = 2 * t;
    int v0 = (c0 < NCHUNK) ? cmat[(size_t)c0 * NBIN + b] : 0;
    int v1 = (c0 + 1 < NCHUNK) ? cmat[(size_t)(c0 + 1) * NBIN + b] : 0;
    int s = v0 + v1;
    ssum[t] = s;
    __syncthreads();
    for (int off = 1; off < 256; off <<= 1) {
        int v = (t >= off) ? ssum[t - off] : 0;
        __syncthreads();
        ssum[t] += v;
        __syncthreads();
    }
    int excl = ssum[t] - s;
    if (c0 < NCHUNK) omat[(size_t)c0 * NBIN + b] = excl;
    if (c0 + 1 < NCHUNK) omat[(size_t)(c0 + 1) * NBIN + b] = excl + v0;
    if (t == 255) btot[b] = ssum[255];
}

// 1 block, 128 threads: scan the 128 bin totals -> bbase[0..128].
__global__ void btot_scan2(const int* __restrict__ btot, int* __restrict__ bbase) {
    __shared__ int sc[NBIN];
    int b = threadIdx.x;   // 128
    int s = btot[b];
    sc[b] = s;
    __syncthreads();
    for (int off = 1; off < NBIN; off <<= 1) {
        int v = (b >= off) ? sc[b - off] : 0;
        __syncthreads();
        sc[b] += v;
        __syncthreads();
    }
    bbase[b] = sc[b] - s;      // exclusive
    if (b == NBIN - 1) bbase[NBIN] = sc[NBIN - 1];
}

__global__ __launch_bounds__(256) void bin_scatter(
        const int* __restrict__ ei, const int* __restrict__ omat,
        const int* __restrict__ bbase, int2* __restrict__ pairs) {
    __shared__ int cnt[NBIN], excl[NBIN], cur[NBIN], gbase[NBIN];
    __shared__ int2 stg[CH];
    __shared__ unsigned char binof[CH];
    const int t = threadIdx.x;
    const int c = blockIdx.x;
    const int c0 = c * CH;
    const int nc = min(CH, EE - c0);
    if (t < NBIN) cnt[t] = 0;
    __syncthreads();
    int msrc[8], mdst[8], mbin[8];
    #pragma unroll
    for (int i = 0; i < 8; ++i) {
        int idx = t + i * 256;
        if (idx < nc) {
            msrc[i] = ei[c0 + idx];
            mdst[i] = ei[EE + c0 + idx];
            mbin[i] = mdst[i] / BINW;
            atomicAdd(&cnt[mbin[i]], 1);
        }
    }
    __syncthreads();
    if (t < NBIN) excl[t] = cnt[t];
    __syncthreads();
    for (int off = 1; off < NBIN; off <<= 1) {
        int v = (t < NBIN && t >= off) ? excl[t - off] : 0;
        __syncthreads();
        if (t < NBIN) excl[t] += v;
        __syncthreads();
    }
    if (t < NBIN) {
        int e2 = excl[t] - cnt[t];
        excl[t] = e2; cur[t] = e2;
        gbase[t] = bbase[t] + omat[c * NBIN + t];
    }
    __syncthreads();
    #pragma unroll
    for (int i = 0; i < 8; ++i) {
        int idx = t + i * 256;
        if (idx < nc) {
            int pos = atomicAdd(&cur[mbin[i]], 1);
            stg[pos] = make_int2(msrc[i], mdst[i]);
            binof[pos] = (unsigned char)mbin[i];
        }
    }
    __syncthreads();
    for (int i = t; i < nc; i += 256) {
        int b = binof[i];
        pairs[gbase[b] + (i - excl[b])] = stg[i];
    }
}

__global__ __launch_bounds__(256) void bin_sort(
        const int2* __restrict__ pairs, const int* __restrict__ bbase,
        int* __restrict__ roff, int* __restrict__ esrc) {
    __shared__ int hist[BINW + 2];
    __shared__ int ssum[256];
    __shared__ int loc[8192];        // 32 KB (bin mean 6250, +24 sigma safe)
    const int b = blockIdx.x;
    const int t = threadIdx.x;
    const int d0 = b * BINW;
    const int nd = (d0 + BINW < NN) ? BINW : (NN - d0);
    const int base = bbase[b];
    const int cnt = bbase[b + 1] - base;
    for (int d = t; d < nd; d += 256) hist[d] = 0;
    __syncthreads();
    for (int i = t; i < cnt; i += 256)
        atomicAdd(&hist[pairs[base + i].y - d0], 1);
    __syncthreads();
    int bi = t * 4;
    int v[4]; int s = 0;
    #pragma unroll
    for (int i = 0; i < 4; ++i) {
        int idx = bi + i;
        v[i] = (idx < nd) ? hist[idx] : 0;
        s += v[i];
    }
    ssum[t] = s;
    __syncthreads();
    for (int off = 1; off < 256; off <<= 1) {
        int val = (t >= off) ? ssum[t - off] : 0;
        __syncthreads();
        ssum[t] += val;
        __syncthreads();
    }
    int run = ssum[t] - s;
    #pragma unroll
    for (int i = 0; i < 4; ++i) {
        int idx = bi + i;
        if (idx < nd) {
            hist[idx] = run;
            roff[d0 + idx] = base + run;
            run += v[i];
        }
    }
    if (b == NBIN - 1 && t == 0) roff[NN] = EE;
    __syncthreads();
    for (int i = t; i < cnt; i += 256) {
        int2 p = pairs[base + i];
        int pos = atomicAdd(&hist[p.y - d0], 1);
        loc[pos] = p.x;
    }
    __syncthreads();
    for (int i = t; i < cnt; i += 256) esrc[base + i] = loc[i];
}

// ---- direct-store epilogue helper (R25) ---------------------------------
// MFMA C layout: node-row = lane&15 (+16*mt), channel = quad*4 + reg.
// Each lane stores its 4 contiguous channels as ONE 8B/16B piece straight
// to global; all 16 pieces of a 128B chunk come from the same wave's
// epilogue -> L2 write-combines to full lines. LDS out-staging deleted.
__device__ __forceinline__ void store_group(
        const floatx4 acc[2][4], int g, int gtype, int ntl,
        const int tiles[4], const float* __restrict__ bp,
        int m0, int ml, int quad,
        unsigned short* __restrict__ qbh, float* __restrict__ sb,
        unsigned short* __restrict__ kvb) {
    #pragma unroll
    for (int t = 0; t < 4; ++t) {
        if (t >= ntl) break;
        int tg = tiles[t];
        int c0 = (tg << 4) + (quad << 2);
        float4 b4 = *(const float4*)(bp + c0);
        #pragma unroll
        for (int mt = 0; mt < 2; ++mt) {
            int node = m0 + mt * 16 + ml;
            if (node >= NN) continue;
            float v0 = acc[mt][t][0] + b4.x;
            float v1 = acc[mt][t][1] + b4.y;
            float v2 = acc[mt][t][2] + b4.z;
            float v3 = acc[mt][t][3] + b4.w;
            if (gtype == 0) {            // q: channel-linear bf16 row
                ushort4 u = {f2bf(v0), f2bf(v1), f2bf(v2), f2bf(v3)};
                *(ushort4*)(qbh + (size_t)node * QBH_W + tg * 16 + quad * 4) = u;
            } else if (gtype == 1) {     // kv interleave (verified vs staged path)
                int j = g - 2;
                int idx = 64 * j + 32 * (t & 1) + 8 * quad + 4 * (t >> 1);
                ushort4 u = {f2bf(v0), f2bf(v1), f2bf(v2), f2bf(v3)};
                *(ushort4*)(kvb + (size_t)node * KV_W + idx) = u;
            } else {                     // skip fp32
                *(float4*)(sb + (size_t)node * SB_W + (tg - 24) * 16 + quad * 4) =
                    make_float4(v0, v1, v2, v3);
            }
        }
    }
}

// ---------------- f16 single-pass MFMA GEMM (layer 0: K=128, fp32 in) ----
__global__ __launch_bounds__(256) void gemm_mfma4(
        const float* __restrict__ X,
        const unsigned short* __restrict__ Wf,
        const float* __restrict__ bp, unsigned short* __restrict__ qbh,
        float* __restrict__ sb, unsigned short* __restrict__ kvb) {
    constexpr int NCH = 4;
    constexpr int K = NCH * 32;
    constexpr int ROWB = 2 * K;              // bytes per X row (f16)
    constexpr int SWZ = 7;                   // row-XOR mask (<<4)
    __shared__ char xlds[128 * ROWB];        // single f16 plane (32 KB) - ONLY LDS
    const int tid = threadIdx.x;
    const int lane = tid & 63;
    const int wv = tid >> 6;
    const int m0b = blockIdx.x << 7;         // block's 128-row base
    const int ml = lane & 15;
    const int quad = lane >> 4;

    // ---- stage X into LDS (fp32 read, f16 convert, XOR-swizzled) ----
    {
        const int NPF = 128 * (K / 4);       // 16-B fp32 pieces
        for (int p = tid; p < NPF; p += 256) {
            int row = p / (K / 4);
            int pc = p % (K / 4);
            int grow = m0b + row;
            if (grow >= NN) grow = NN - 1;
            float4 v = *(const float4*)((const char*)X + (size_t)grow * (4 * K) + pc * 16);
            ushort4 h = {f2h(v.x), f2h(v.y), f2h(v.z), f2h(v.w)};
            int addr = row * ROWB + ((pc * 8) ^ ((row & SWZ) << 4));
            *(ushort4*)(xlds + addr) = h;
        }
    }
    __syncthreads();

    const int m0 = m0b + (wv << 5);          // this wave's 32-row base
    const int rowL0 = (wv << 5) + ml;        // local row, half 0
    const int rowL1 = rowL0 + 16;            // local row, half 1

    for (int g = 0; g < 7; ++g) {
        int tiles[4]; int ntl = 4; int gtype;     // 0=q, 1=kv, 2=skip
        if (g < 2) {
            gtype = 0;
            #pragma unroll
            for (int i = 0; i < 4; ++i) tiles[i] = 4 * g + i;
        } else if (g < 6) {
            gtype = 1;
            int j = g - 2;
            tiles[0] = 8 + 2 * j; tiles[1] = 9 + 2 * j;
            tiles[2] = 16 + 2 * j; tiles[3] = 17 + 2 * j;
        } else {
            gtype = 2; ntl = 2;
            tiles[0] = 24; tiles[1] = 25; tiles[2] = 24; tiles[3] = 25;
        }

        floatx4 acc[2][4] = {};

        #pragma unroll
        for (int c = 0; c < NCH; ++c) {
            int colb = (c * 64 + quad * 16);
            int a0 = rowL0 * ROWB + (colb ^ ((rowL0 & SWZ) << 4));
            int a1 = rowL1 * ROWB + (colb ^ ((rowL1 & SWZ) << 4));
            half8 x0 = *(const half8*)(xlds + a0);
            half8 x1 = *(const half8*)(xlds + a1);
            #pragma unroll
            for (int t = 0; t < 4; ++t) {
                if (t < ntl) {
                    size_t boff = (((size_t)c * NTILE + tiles[t]) * 64 + lane) * 8;
                    half8 w = *(const half8*)(Wf + boff);
                    acc[0][t] = __builtin_amdgcn_mfma_f32_16x16x32_f16(w, x0, acc[0][t], 0, 0, 0);
                    acc[1][t] = __builtin_amdgcn_mfma_f32_16x16x32_f16(w, x1, acc[1][t], 0, 0, 0);
                }
            }
        }

        store_group(acc, g, gtype, ntl, tiles, bp, m0, ml, quad, qbh, sb, kvb);
    }
}

// ---------------- layer-1 GEMM (K=32): no LDS at all ---------------------
__global__ __launch_bounds__(256) void gemm_small(
        const unsigned short* __restrict__ hf,
        const unsigned short* __restrict__ Wf,
        const float* __restrict__ bp, unsigned short* __restrict__ qbh,
        float* __restrict__ sb, unsigned short* __restrict__ kvb) {
    const int tid = threadIdx.x;
    const int lane = tid & 63;
    const int wv = tid >> 6;
    const int m0 = (blockIdx.x << 7) + (wv << 5);
    const int ml = lane & 15;
    const int quad = lane >> 4;

    int r0 = m0 + ml;       if (r0 >= NN) r0 = NN - 1;
    int r1 = m0 + 16 + ml;  if (r1 >= NN) r1 = NN - 1;
    half8 x0 = *(const half8*)(hf + (size_t)r0 * HID + quad * 8);
    half8 x1 = *(const half8*)(hf + (size_t)r1 * HID + quad * 8);

    for (int g = 0; g < 7; ++g) {
        int tiles[4]; int ntl = 4; int gtype;
        if (g < 2) {
            gtype = 0;
            #pragma unroll
            for (int i = 0; i < 4; ++i) tiles[i] = 4 * g + i;
        } else if (g < 6) {
            gtype = 1;
            int j = g - 2;
            tiles[0] = 8 + 2 * j; tiles[1] = 9 + 2 * j;
            tiles[2] = 16 + 2 * j; tiles[3] = 17 + 2 * j;
        } else {
            gtype = 2; ntl = 2;
            tiles[0] = 24; tiles[1] = 25; tiles[2] = 24; tiles[3] = 25;
        }

        floatx4 acc[2][4] = {};
        #pragma unroll
        for (int t = 0; t < 4; ++t) {
            if (t < ntl) {
                size_t boff = ((size_t)tiles[t] * 64 + lane) * 8;
                half8 w = *(const half8*)(Wf + boff);
                acc[0][t] = __builtin_amdgcn_mfma_f32_16x16x32_f16(w, x0, acc[0][t], 0, 0, 0);
                acc[1][t] = __builtin_amdgcn_mfma_f32_16x16x32_f16(w, x1, acc[1][t], 0, 0, 0);
            }
        }

        store_group(acc, g, gtype, ntl, tiles, bp, m0, ml, quad, qbh, sb, kvb);
    }
}

// ---------------- fused attention: ONE NODE PER HALF-WAVE ----------------
// R22 structure. FINAL=false: layer 0, writes h as one f16 plane.
// FINAL=true: layer 1, fuses the output linear via a 1-KB LDS h-buffer.
#define ATTN_STEP(u) {                                                       \
    float k0 = bf_lo((u).x), k1 = bf_hi((u).x);                              \
    float k2 = bf_lo((u).y), k3 = bf_hi((u).y);                              \
    float v0 = bf_lo((u).z), v1 = bf_hi((u).z);                              \
    float v2 = bf_lo((u).w), v3 = bf_hi((u).w);                              \
    float part = q4.x * k0 + q4.y * k1 + q4.z * k2 + q4.w * k3;              \
    part += __shfl_xor(part, 1);                                             \
    part += __shfl_xor(part, 2);                                             \
    part += __shfl_xor(part, 4);                                             \
    float p = exp2f(part);                                                   \
    s += p;                                                                  \
    acc.x += p * v0;                                                         \
    acc.y += p * v1;                                                         \
    acc.z += p * v2;                                                         \
    acc.w += p * v3; }

template <bool FINAL>
__global__ __launch_bounds__(256) void fused_attn(
        const unsigned short* __restrict__ qbh, const float* __restrict__ sb,
        const unsigned short* __restrict__ kvb,
        const int* __restrict__ roff, const int* __restrict__ esrc,
        unsigned short* __restrict__ hf,
        const float* __restrict__ Wout, const float* __restrict__ bout,
        float* __restrict__ outp) {
    __shared__ float hbuf[8][32];      // FINAL only: block's 8 node h rows
    const int tid = threadIdx.x;
    const int lane = tid & 63;
    const int w = (blockIdx.x * blockDim.x + tid) >> 6;   // wave id
    const int hw = lane >> 5;
    const int n = 2 * w + hw;          // this half-wave's node
    // NN = attn_blocks*8 exactly -> n < NN always (guard kept for safety).
    if (n < NN) {
    const int kl = lane & 31;

    ushort4 qu = *(const ushort4*)(qbh + (size_t)n * QBH_W + 4 * kl);
    float4 q4 = make_float4(bf2f(qu.x) * QSCALE, bf2f(qu.y) * QSCALE,
                            bf2f(qu.z) * QSCALE, bf2f(qu.w) * QSCALE);
    float4 sk = *(const float4*)(sb + (size_t)n * SB_W + 4 * (kl & 7));

    float s = 0.f;
    float4 acc = make_float4(0.f, 0.f, 0.f, 0.f);
    const int e0 = roff[n];
    const int cnt = roff[n + 1] - e0;
    int i = 0;
    for (; i + 4 <= cnt; i += 4) {
        int b0 = esrc[e0 + i];
        int b1 = esrc[e0 + i + 1];
        int b2 = esrc[e0 + i + 2];
        int b3 = esrc[e0 + i + 3];
        uint4 u0 = *(const uint4*)(kvb + (size_t)b0 * KV_W + 8 * kl);
        uint4 u1 = *(const uint4*)(kvb + (size_t)b1 * KV_W + 8 * kl);
        uint4 u2 = *(const uint4*)(kvb + (size_t)b2 * KV_W + 8 * kl);
        uint4 u3 = *(const uint4*)(kvb + (size_t)b3 * KV_W + 8 * kl);
        ATTN_STEP(u0); ATTN_STEP(u1); ATTN_STEP(u2); ATTN_STEP(u3);
    }
    for (; i < cnt; ++i) {
        int b0 = esrc[e0 + i];
        uint4 u0 = *(const uint4*)(kvb + (size_t)b0 * KV_W + 8 * kl);
        ATTN_STEP(u0);
    }

    float inv = (s > 0.f) ? 1.f / s : 0.f;
    float4 o;
    o.x = acc.x * inv; o.y = acc.y * inv; o.z = acc.z * inv; o.w = acc.w * inv;
    o.x += __shfl_xor(o.x, 8);  o.y += __shfl_xor(o.y, 8);  o.z += __shfl_xor(o.z, 8);  o.w += __shfl_xor(o.w, 8);
    o.x += __shfl_xor(o.x, 16); o.y += __shfl_xor(o.y, 16); o.z += __shfl_xor(o.z, 16); o.w += __shfl_xor(o.w, 16);
    if (kl < 8) {
        float4 rr;
        rr.x = fmaxf(o.x * 0.25f + sk.x, 0.f);
        rr.y = fmaxf(o.y * 0.25f + sk.y, 0.f);
        rr.z = fmaxf(o.z * 0.25f + sk.z, 0.f);
        rr.w = fmaxf(o.w * 0.25f + sk.w, 0.f);
        int c0 = 4 * kl;
        if constexpr (FINAL) {
            int slot = (tid >> 6) * 2 + hw;          // 0..7 within block
            *(float4*)(&hbuf[slot][c0]) = rr;
        } else {
            ushort4 uh = {f2h(rr.x), f2h(rr.y), f2h(rr.z), f2h(rr.w)};
            *(ushort4*)(hf + (size_t)n * HID + c0) = uh;
        }
    }
    }
    if constexpr (FINAL) {
        __syncthreads();
        if (tid < 128) {
            int slot = tid >> 4;
            int j = tid & 15;
            int n2 = blockIdx.x * 8 + slot;
            if (n2 < NN) {
                float a = bout[j];
                #pragma unroll
                for (int k = 0; k < HID; ++k)
                    a += hbuf[slot][k] * Wout[k * OUT_DIM + j];
                outp[(size_t)n2 * OUT_DIM + j] = a;
            }
        }
    }
}

extern "C" void kernel_launch(void* const* d_in, const int* in_sizes, int n_in,
                              void* d_out, int out_size, void* d_ws, size_t ws_size,
                              hipStream_t stream) {
    const float* x  = (const float*)d_in[0];
    const int*   ei = (const int*)d_in[1];
    const float* l0w[8]; const float* l1w[8];
    for (int i = 0; i < 8; ++i) { l0w[i] = (const float*)d_in[2 + i]; l1w[i] = (const float*)d_in[10 + i]; }
    const float* Wout = (const float*)d_in[18];
    const float* bout = (const float*)d_in[19];
    float* out = (float*)d_out;

    // workspace layout
    float* ws = (float*)d_ws;
    float* sb   = ws;                           // NN*32 floats
    float* bp0  = sb + (size_t)NN * SB_W;       // 416
    float* bp1  = bp0 + COLS;                   // 416
    unsigned short* qbh  = (unsigned short*)(bp1 + COLS);    // NN*128 bf16
    unsigned short* kvb  = qbh + (size_t)NN * QBH_W;         // NN*256 bf16
    unsigned short* hf   = kvb + (size_t)NN * KV_W;          // NN*32 f16
    unsigned short* Wf0  = hf + (size_t)NN * HID;            // 4*26*64*8
    unsigned short* Wf1  = Wf0 + 4 * NTILE * 64 * 8;         // 1*26*64*8
    int* ibase  = (int*)(Wf1 + NTILE * 64 * 8);
    int* roff    = ibase;                       // NN+1
    int* esrc    = roff + NN + 1;               // EE
    int* cmat    = esrc + EE;                   // NCHUNK*NBIN (~200KB)
    int* omat    = cmat + NCHUNK * NBIN;        // NCHUNK*NBIN
    int* bbase   = omat + NCHUNK * NBIN;        // NBIN+1
    int* btot    = bbase + NBIN + 2;            // NBIN
    int2* pairs  = (int2*)(btot + NBIN);        // EE int2 (6.4 MB)

    // pack BOTH layers' weights in one launch
    pack_frag2<<<(5 * NTILE * 64 + 255) / 256, 256, 0, stream>>>(
        l0w[0], l0w[2], l0w[4], l0w[6], l0w[1], l0w[3], l0w[5], l0w[7],
        l1w[0], l1w[2], l1w[4], l1w[6], l1w[1], l1w[3], l1w[5], l1w[7],
        Wf0, bp0, Wf1, bp1);

    // ---- CSR build: atomic-free deterministic bin sort (5 kernels) ----
    chunk_hist<<<NCHUNK, 256, 0, stream>>>(ei, cmat);
    bin_prefix<<<NBIN, 256, 0, stream>>>(cmat, omat, btot);
    btot_scan2<<<1, NBIN, 0, stream>>>(btot, bbase);
    bin_scatter<<<NCHUNK, 256, 0, stream>>>(ei, omat, bbase, pairs);
    bin_sort<<<NBIN, 256, 0, stream>>>(pairs, bbase, roff, esrc);

    const int gemm_blocks = (NN + 127) / 128;    // 782
    const int attn_blocks = ((NN + 1) / 2 * 64 + 255) / 256;   // 12500 (x8 = NN)

    // layer 0: gemm reads X fp32 directly (in-staging f16 convert)
    gemm_mfma4<<<gemm_blocks, 256, 0, stream>>>(x, Wf0, bp0, qbh, sb, kvb);
    fused_attn<false><<<attn_blocks, 256, 0, stream>>>(
        qbh, sb, kvb, roff, esrc, hf, (const float*)nullptr,
        (const float*)nullptr, (float*)nullptr);

    // layer 1: gemm reads h f16 plane straight from global (no LDS)
    gemm_small<<<gemm_blocks, 256, 0, stream>>>(hf, Wf1, bp1, qbh, sb, kvb);
    fused_attn<true><<<attn_blocks, 256, 0, stream>>>(
        qbh, sb, kvb, roff, esrc, (unsigned short*)nullptr, Wout, bout, out);
}

// Round 15
// 340.270 us; speedup vs baseline: 1.0603x; 1.0603x over previous
//
#include <hip/hip_runtime.h>
#include <math.h>

#define NN 100000
#define EE 800000
#define IN_DIM 128
#define HID 32
#define HEADS 4
#define QKV 128         // HEADS*HID
#define COLS 416        // 3*QKV + HID (q|k|v|skip)
#define QBH_W 128       // q bf16 row (256 B)
#define SB_W 32         // skip fp32 row (128 B)
#define KV_W 256        // interleaved bf16: 32 groups of [k x4 | v x4] (512-B rows)
#define OUT_DIM 16
#define NTILE 26        // 416/16 col-tiles
#define NBIN 128        // dst-range bins for CSR sort
#define BINW 782        // ceil(NN/NBIN); 128*782 = 100096 >= NN
#define CH 2048         // edges per chunk
#define NCHUNK 391      // ceil(EE/CH)
#define PACKB 33        // blocks for weight pack (8320 threads / 256)
// (1/sqrt(32)) * log2(e): pre-folded into q so p = exp2(part)
#define QSCALE 0.25503512f

typedef __attribute__((ext_vector_type(8))) _Float16 half8;
typedef __attribute__((ext_vector_type(4))) float floatx4;

__device__ __forceinline__ unsigned short f2bf(float f) {
    unsigned int u = __float_as_uint(f);
    unsigned int r = (u + 0x7FFF + ((u >> 16) & 1)) >> 16;   // RNE
    return (unsigned short)r;
}
__device__ __forceinline__ float bf2f(unsigned short h) {
    return __uint_as_float((unsigned int)h << 16);
}
__device__ __forceinline__ float bf_lo(unsigned int d) {
    return __uint_as_float(d << 16);
}
__device__ __forceinline__ float bf_hi(unsigned int d) {
    return __uint_as_float(d & 0xFFFF0000u);
}
__device__ __forceinline__ unsigned short f2h(float f) {
    _Float16 h = (_Float16)f;                  // v_cvt_f16_f32, RNE
    return __builtin_bit_cast(unsigned short, h);
}

// ---------------- fragment-pack helper (f16 single plane) + biases -------
// Wf[((c*26 + t)*64 + lane)*8 + j] = W[(c*32 + (lane>>4)*8 + j)][t*16 + (lane&15)]
__device__ __forceinline__ void pack_one(
        const float* __restrict__ Wq, const float* __restrict__ Wk,
        const float* __restrict__ Wv, const float* __restrict__ Ws,
        const float* __restrict__ bq, const float* __restrict__ bk,
        const float* __restrict__ bv, const float* __restrict__ bs,
        unsigned short* __restrict__ Wf, float* __restrict__ bp,
        int K, int idx) {
    if (idx < COLS) {
        float b;
        if (idx < 128)      b = bq[idx];
        else if (idx < 256) b = bk[idx - 128];
        else if (idx < 384) b = bv[idx - 256];
        else                b = bs[idx - 384];
        bp[idx] = b;
    }
    int nch = K >> 5;
    if (idx >= nch * NTILE * 64) return;
    int lane = idx & 63;
    int tt = (idx >> 6) % NTILE;
    int c = idx / (NTILE * 64);
    int k0 = c * 32 + (lane >> 4) * 8;
    int col = tt * 16 + (lane & 15);
    #pragma unroll
    for (int j = 0; j < 8; ++j) {
        int k = k0 + j;
        float w;
        if (col < 128)      w = Wq[(size_t)k * 128 + col];
        else if (col < 256) w = Wk[(size_t)k * 128 + (col - 128)];
        else if (col < 384) w = Wv[(size_t)k * 128 + (col - 256)];
        else                w = Ws[(size_t)k * 32 + (col - 384)];
        Wf[(size_t)idx * 8 + j] = f2h(w);
    }
}

// ---------------- merged: chunk histogram (blocks 0..NCHUNK-1) + weight
// pack (blocks NCHUNK..NCHUNK+PACKB-1). One launch instead of two.
__global__ __launch_bounds__(256) void hist_pack(
        const int* __restrict__ ei, int* __restrict__ cmat,
        const float* __restrict__ Wq0, const float* __restrict__ Wk0,
        const float* __restrict__ Wv0, const float* __restrict__ Ws0,
        const float* __restrict__ bq0, const float* __restrict__ bk0,
        const float* __restrict__ bv0, const float* __restrict__ bs0,
        const float* __restrict__ Wq1, const float* __restrict__ Wk1,
        const float* __restrict__ Wv1, const float* __restrict__ Ws1,
        const float* __restrict__ bq1, const float* __restrict__ bk1,
        const float* __restrict__ bv1, const float* __restrict__ bs1,
        unsigned short* __restrict__ Wf0, float* __restrict__ bp0,
        unsigned short* __restrict__ Wf1, float* __restrict__ bp1) {
    const int t = threadIdx.x;
    if (blockIdx.x < NCHUNK) {
        __shared__ int cnt[NBIN];
        const int c = blockIdx.x;
        const int c0 = c * CH;
        const int nc = min(CH, EE - c0);
        if (t < NBIN) cnt[t] = 0;
        __syncthreads();
        for (int i = t; i < nc; i += 256)
            atomicAdd(&cnt[ei[EE + c0 + i] / BINW], 1);
        __syncthreads();
        if (t < NBIN) cmat[c * NBIN + t] = cnt[t];
        return;
    }
    const int L0N = 4 * NTILE * 64;   // 6656
    int gid = (blockIdx.x - NCHUNK) * 256 + t;
    if (gid < L0N) {
        pack_one(Wq0, Wk0, Wv0, Ws0, bq0, bk0, bv0, bs0, Wf0, bp0, 128, gid);
    } else {
        pack_one(Wq1, Wk1, Wv1, Ws1, bq1, bk1, bv1, bs1, Wf1, bp1, 32, gid - L0N);
    }
}

// 128 blocks (one per bin): block-scan over the 391 chunk counts ->
// omat[c][b] = LOCAL write base; btot[b] = bin total.
__global__ __launch_bounds__(256) void bin_prefix(
        const int* __restrict__ cmat, int* __restrict__ omat,
        int* __restrict__ btot) {
    __shared__ int ssum[256];
    const int b = blockIdx.x;
    const int t = threadIdx.x;
    int c0 = 2 * t;
    int v0 = (c0 < NCHUNK) ? cmat[(size_t)c0 * NBIN + b] : 0;
    int v1 = (c0 + 1 < NCHUNK) ? cmat[(size_t)(c0 + 1) * NBIN + b] : 0;
    int s = v0 + v1;
    ssum[t] = s;
    __syncthreads();
    for (int off = 1; off < 256; off <<= 1) {
        int v = (t >= off) ? ssum[t - off] : 0;
        __syncthreads();
        ssum[t] += v;
        __syncthreads();
    }
    int excl = ssum[t] - s;
    if (c0 < NCHUNK) omat[(size_t)c0 * NBIN + b] = excl;
    if (c0 + 1 < NCHUNK) omat[(size_t)(c0 + 1) * NBIN + b] = excl + v0;
    if (t == 255) btot[b] = ssum[255];
}

// local bin-base scan helper: bb[0..NBIN] (exclusive) from btot, in LDS.
__device__ __forceinline__ void local_bbase(const int* __restrict__ btot,
                                            int* bb /*NBIN+1 LDS*/) {
    int t = threadIdx.x;
    __shared__ int sc[NBIN];
    int s = 0;
    if (t < NBIN) { s = btot[t]; sc[t] = s; }
    __syncthreads();
    for (int off = 1; off < NBIN; off <<= 1) {
        int v = (t < NBIN && t >= off) ? sc[t - off] : 0;
        __syncthreads();
        if (t < NBIN) sc[t] += v;
        __syncthreads();
    }
    if (t < NBIN) bb[t] = sc[t] - s;
    if (t == NBIN - 1) bb[NBIN] = sc[NBIN - 1];
    __syncthreads();
}

__global__ __launch_bounds__(256) void bin_scatter(
        const int* __restrict__ ei, const int* __restrict__ omat,
        const int* __restrict__ btot, int2* __restrict__ pairs) {
    __shared__ int bb[NBIN + 1];
    __shared__ int cnt[NBIN], excl[NBIN], cur[NBIN], gbase[NBIN];
    __shared__ int2 stg[CH];
    __shared__ unsigned char binof[CH];
    const int t = threadIdx.x;
    const int c = blockIdx.x;
    const int c0 = c * CH;
    const int nc = min(CH, EE - c0);
    local_bbase(btot, bb);
    if (t < NBIN) cnt[t] = 0;
    __syncthreads();
    int msrc[8], mdst[8], mbin[8];
    #pragma unroll
    for (int i = 0; i < 8; ++i) {
        int idx = t + i * 256;
        if (idx < nc) {
            msrc[i] = ei[c0 + idx];
            mdst[i] = ei[EE + c0 + idx];
            mbin[i] = mdst[i] / BINW;
            atomicAdd(&cnt[mbin[i]], 1);
        }
    }
    __syncthreads();
    if (t < NBIN) excl[t] = cnt[t];
    __syncthreads();
    for (int off = 1; off < NBIN; off <<= 1) {
        int v = (t < NBIN && t >= off) ? excl[t - off] : 0;
        __syncthreads();
        if (t < NBIN) excl[t] += v;
        __syncthreads();
    }
    if (t < NBIN) {
        int e2 = excl[t] - cnt[t];
        excl[t] = e2; cur[t] = e2;
        gbase[t] = bb[t] + omat[c * NBIN + t];
    }
    __syncthreads();
    #pragma unroll
    for (int i = 0; i < 8; ++i) {
        int idx = t + i * 256;
        if (idx < nc) {
            int pos = atomicAdd(&cur[mbin[i]], 1);
            stg[pos] = make_int2(msrc[i], mdst[i]);
            binof[pos] = (unsigned char)mbin[i];
        }
    }
    __syncthreads();
    for (int i = t; i < nc; i += 256) {
        int b = binof[i];
        pairs[gbase[b] + (i - excl[b])] = stg[i];
    }
}

__global__ __launch_bounds__(256) void bin_sort(
        const int2* __restrict__ pairs, const int* __restrict__ btot,
        int* __restrict__ roff, int* __restrict__ esrc) {
    __shared__ int bb[NBIN + 1];
    __shared__ int hist[BINW + 2];
    __shared__ int ssum[256];
    __shared__ int loc[8192];        // 32 KB (bin mean 6250, +24 sigma safe)
    const int b = blockIdx.x;
    const int t = threadIdx.x;
    local_bbase(btot, bb);
    const int d0 = b * BINW;
    const int nd = (d0 + BINW < NN) ? BINW : (NN - d0);
    const int base = bb[b];
    const int cnt = bb[b + 1] - base;
    for (int d = t; d < nd; d += 256) hist[d] = 0;
    __syncthreads();
    for (int i = t; i < cnt; i += 256)
        atomicAdd(&hist[pairs[base + i].y - d0], 1);
    __syncthreads();
    int bi = t * 4;
    int v[4]; int s = 0;
    #pragma unroll
    for (int i = 0; i < 4; ++i) {
        int idx = bi + i;
        v[i] = (idx < nd) ? hist[idx] : 0;
        s += v[i];
    }
    ssum[t] = s;
    __syncthreads();
    for (int off = 1; off < 256; off <<= 1) {
        int val = (t >= off) ? ssum[t - off] : 0;
        __syncthreads();
        ssum[t] += val;
        __syncthreads();
    }
    int run = ssum[t] - s;
    #pragma unroll
    for (int i = 0; i < 4; ++i) {
        int idx = bi + i;
        if (idx < nd) {
            hist[idx] = run;
            roff[d0 + idx] = base + run;
            run += v[i];
        }
    }
    if (b == NBIN - 1 && t == 0) roff[NN] = EE;
    __syncthreads();
    for (int i = t; i < cnt; i += 256) {
        int2 p = pairs[base + i];
        int pos = atomicAdd(&hist[p.y - d0], 1);
        loc[pos] = p.x;
    }
    __syncthreads();
    for (int i = t; i < cnt; i += 256) esrc[base + i] = loc[i];
}

// ---------------- f16 single-pass MFMA GEMM (layer 0: K=128, fp32 in) ----
// R24-proven: LDS-staged epilogue (the staging IS the fragment->line
// transpose; R25's direct store scattered 8B shards and regressed).
__global__ __launch_bounds__(256, 3) void gemm_mfma4(
        const float* __restrict__ X,
        const unsigned short* __restrict__ Wf,
        const float* __restrict__ bp, unsigned short* __restrict__ qbh,
        float* __restrict__ sb, unsigned short* __restrict__ kvb) {
    constexpr int NCH = 4;
    constexpr int K = NCH * 32;
    constexpr int ROWB = 2 * K;              // bytes per X row (f16)
    constexpr int SWZ = 7;                   // row-XOR mask (<<4)
    __shared__ char xlds[128 * ROWB];        // single f16 plane (32 KB)
    __shared__ char olds[4][32][128];        // per-wave out staging (16 KB)
    const int tid = threadIdx.x;
    const int lane = tid & 63;
    const int wv = tid >> 6;
    const int m0b = blockIdx.x << 7;         // block's 128-row base
    const int ml = lane & 15;
    const int quad = lane >> 4;

    // ---- stage X into LDS (fp32 read, f16 convert, XOR-swizzled) ----
    {
        const int NPF = 128 * (K / 4);       // 16-B fp32 pieces
        for (int p = tid; p < NPF; p += 256) {
            int row = p / (K / 4);
            int pc = p % (K / 4);
            int grow = m0b + row;
            if (grow >= NN) grow = NN - 1;
            float4 v = *(const float4*)((const char*)X + (size_t)grow * (4 * K) + pc * 16);
            ushort4 h = {f2h(v.x), f2h(v.y), f2h(v.z), f2h(v.w)};
            int addr = row * ROWB + ((pc * 8) ^ ((row & SWZ) << 4));
            *(ushort4*)(xlds + addr) = h;
        }
    }
    __syncthreads();

    const int m0 = m0b + (wv << 5);          // this wave's 32-row base
    const int rowL0 = (wv << 5) + ml;        // local row, half 0
    const int rowL1 = rowL0 + 16;            // local row, half 1
    char* myl = &olds[wv][0][0];

    for (int g = 0; g < 7; ++g) {
        int tiles[4]; int ntl = 4; int gtype;     // 0=q, 1=kv, 2=skip
        if (g < 2) {
            gtype = 0;
            #pragma unroll
            for (int i = 0; i < 4; ++i) tiles[i] = 4 * g + i;
        } else if (g < 6) {
            gtype = 1;
            int j = g - 2;
            tiles[0] = 8 + 2 * j; tiles[1] = 9 + 2 * j;
            tiles[2] = 16 + 2 * j; tiles[3] = 17 + 2 * j;
        } else {
            gtype = 2; ntl = 2;
            tiles[0] = 24; tiles[1] = 25; tiles[2] = 24; tiles[3] = 25;
        }

        floatx4 acc[2][4] = {};

        #pragma unroll
        for (int c = 0; c < NCH; ++c) {
            int colb = (c * 64 + quad * 16);
            int a0 = rowL0 * ROWB + (colb ^ ((rowL0 & SWZ) << 4));
            int a1 = rowL1 * ROWB + (colb ^ ((rowL1 & SWZ) << 4));
            half8 x0 = *(const half8*)(xlds + a0);
            half8 x1 = *(const half8*)(xlds + a1);
            #pragma unroll
            for (int t = 0; t < 4; ++t) {
                if (t < ntl) {
                    size_t boff = (((size_t)c * NTILE + tiles[t]) * 64 + lane) * 8;
                    half8 w = *(const half8*)(Wf + boff);
                    acc[0][t] = __builtin_amdgcn_mfma_f32_16x16x32_f16(w, x0, acc[0][t], 0, 0, 0);
                    acc[1][t] = __builtin_amdgcn_mfma_f32_16x16x32_f16(w, x1, acc[1][t], 0, 0, 0);
                }
            }
        }

        // ---- stage into wave-private LDS in FINAL byte order (XOR pitch-128) ----
        #pragma unroll
        for (int t = 0; t < 4; ++t) {
            if (t >= ntl) break;
            int tg = tiles[t];
            int c0 = (tg << 4) + (quad << 2);
            float4 b4 = *(const float4*)(bp + c0);
            #pragma unroll
            for (int mt = 0; mt < 2; ++mt) {
                int row = mt * 16 + ml;
                int sz = (row & 7) << 4;
                float v0 = acc[mt][t][0] + b4.x;
                float v1 = acc[mt][t][1] + b4.y;
                float v2 = acc[mt][t][2] + b4.z;
                float v3 = acc[mt][t][3] + b4.w;
                if (gtype == 2) {
                    *(float4*)(myl + row * 128 + ((64 * t + 16 * quad) ^ sz)) =
                        make_float4(v0, v1, v2, v3);
                } else {
                    ushort4 u = {f2bf(v0), f2bf(v1), f2bf(v2), f2bf(v3)};
                    int off;
                    if (gtype == 0) off = 32 * t + 8 * quad;
                    else off = 64 * (t & 1) + 16 * quad + 8 * (t >> 1);
                    *(ushort4*)(myl + row * 128 + (off ^ sz)) = u;
                }
            }
        }
        // wave-private RAW/WAR: DS pipe is in-order per wave.

        const int lr = lane >> 3;
        const int lc = (lane & 7) * 16;
        #pragma unroll
        for (int i = 0; i < 4; ++i) {
            int row = i * 8 + lr;
            uint4 d = *(const uint4*)(myl + row * 128 + (lc ^ (lr << 4)));
            int node = m0 + row;
            if (node < NN) {
                char* dst;
                if (gtype == 0)      dst = (char*)qbh + (size_t)node * 256 + g * 128 + lc;
                else if (gtype == 1) dst = (char*)kvb + (size_t)node * 512 + (g - 2) * 128 + lc;
                else                 dst = (char*)sb + (size_t)node * 128 + lc;
                *(uint4*)dst = d;
            }
        }
    }
}

// ---------------- layer-1 GEMM (K=32): A from global, staged epilogue ----
__global__ __launch_bounds__(256) void gemm_small(
        const unsigned short* __restrict__ hf,
        const unsigned short* __restrict__ Wf,
        const float* __restrict__ bp, unsigned short* __restrict__ qbh,
        float* __restrict__ sb, unsigned short* __restrict__ kvb) {
    __shared__ char olds[4][32][128];        // per-wave out staging
    const int tid = threadIdx.x;
    const int lane = tid & 63;
    const int wv = tid >> 6;
    const int m0 = (blockIdx.x << 7) + (wv << 5);
    const int ml = lane & 15;
    const int quad = lane >> 4;
    char* myl = &olds[wv][0][0];

    int r0 = m0 + ml;       if (r0 >= NN) r0 = NN - 1;
    int r1 = m0 + 16 + ml;  if (r1 >= NN) r1 = NN - 1;
    half8 x0 = *(const half8*)(hf + (size_t)r0 * HID + quad * 8);
    half8 x1 = *(const half8*)(hf + (size_t)r1 * HID + quad * 8);

    for (int g = 0; g < 7; ++g) {
        int tiles[4]; int ntl = 4; int gtype;
        if (g < 2) {
            gtype = 0;
            #pragma unroll
            for (int i = 0; i < 4; ++i) tiles[i] = 4 * g + i;
        } else if (g < 6) {
            gtype = 1;
            int j = g - 2;
            tiles[0] = 8 + 2 * j; tiles[1] = 9 + 2 * j;
            tiles[2] = 16 + 2 * j; tiles[3] = 17 + 2 * j;
        } else {
            gtype = 2; ntl = 2;
            tiles[0] = 24; tiles[1] = 25; tiles[2] = 24; tiles[3] = 25;
        }

        floatx4 acc[2][4] = {};
        #pragma unroll
        for (int t = 0; t < 4; ++t) {
            if (t < ntl) {
                size_t boff = ((size_t)tiles[t] * 64 + lane) * 8;
                half8 w = *(const half8*)(Wf + boff);
                acc[0][t] = __builtin_amdgcn_mfma_f32_16x16x32_f16(w, x0, acc[0][t], 0, 0, 0);
                acc[1][t] = __builtin_amdgcn_mfma_f32_16x16x32_f16(w, x1, acc[1][t], 0, 0, 0);
            }
        }

        #pragma unroll
        for (int t = 0; t < 4; ++t) {
            if (t >= ntl) break;
            int tg = tiles[t];
            int c0 = (tg << 4) + (quad << 2);
            float4 b4 = *(const float4*)(bp + c0);
            #pragma unroll
            for (int mt = 0; mt < 2; ++mt) {
                int row = mt * 16 + ml;
                int sz = (row & 7) << 4;
                float v0 = acc[mt][t][0] + b4.x;
                float v1 = acc[mt][t][1] + b4.y;
                float v2 = acc[mt][t][2] + b4.z;
                float v3 = acc[mt][t][3] + b4.w;
                if (gtype == 2) {
                    *(float4*)(myl + row * 128 + ((64 * t + 16 * quad) ^ sz)) =
                        make_float4(v0, v1, v2, v3);
                } else {
                    ushort4 u = {f2bf(v0), f2bf(v1), f2bf(v2), f2bf(v3)};
                    int off;
                    if (gtype == 0) off = 32 * t + 8 * quad;
                    else off = 64 * (t & 1) + 16 * quad + 8 * (t >> 1);
                    *(ushort4*)(myl + row * 128 + (off ^ sz)) = u;
                }
            }
        }
        // wave-private RAW/WAR: in-order DS pipe.

        const int lr = lane >> 3;
        const int lc = (lane & 7) * 16;
        #pragma unroll
        for (int i = 0; i < 4; ++i) {
            int row = i * 8 + lr;
            uint4 d = *(const uint4*)(myl + row * 128 + (lc ^ (lr << 4)));
            int node = m0 + row;
            if (node < NN) {
                char* dst;
                if (gtype == 0)      dst = (char*)qbh + (size_t)node * 256 + g * 128 + lc;
                else if (gtype == 1) dst = (char*)kvb + (size_t)node * 512 + (g - 2) * 128 + lc;
                else                 dst = (char*)sb + (size_t)node * 128 + lc;
                *(uint4*)dst = d;
            }
        }
    }
}

// ---------------- fused attention: ONE NODE PER HALF-WAVE ----------------
// FINAL=false: layer 0, writes h as one f16 plane.
// FINAL=true: layer 1, fuses the output linear via a 1-KB LDS h-buffer.
#define ATTN_STEP(u) {                                                       \
    float k0 = bf_lo((u).x), k1 = bf_hi((u).x);                              \
    float k2 = bf_lo((u).y), k3 = bf_hi((u).y);                              \
    float v0 = bf_lo((u).z), v1 = bf_hi((u).z);                              \
    float v2 = bf_lo((u).w), v3 = bf_hi((u).w);                              \
    float part = q4.x * k0 + q4.y * k1 + q4.z * k2 + q4.w * k3;              \
    part += __shfl_xor(part, 1);                                             \
    part += __shfl_xor(part, 2);                                             \
    part += __shfl_xor(part, 4);                                             \
    float p = exp2f(part);                                                   \
    s += p;                                                                  \
    acc.x += p * v0;                                                         \
    acc.y += p * v1;                                                         \
    acc.z += p * v2;                                                         \
    acc.w += p * v3; }

template <bool FINAL>
__global__ __launch_bounds__(256) void fused_attn(
        const unsigned short* __restrict__ qbh, const float* __restrict__ sb,
        const unsigned short* __restrict__ kvb,
        const int* __restrict__ roff, const int* __restrict__ esrc,
        unsigned short* __restrict__ hf,
        const float* __restrict__ Wout, const float* __restrict__ bout,
        float* __restrict__ outp) {
    __shared__ float hbuf[8][32];      // FINAL only: block's 8 node h rows
    const int tid = threadIdx.x;
    const int lane = tid & 63;
    const int w = (blockIdx.x * blockDim.x + tid) >> 6;   // wave id
    const int hw = lane >> 5;
    const int n = 2 * w + hw;          // this half-wave's node
    // NN = attn_blocks*8 exactly -> n < NN always (guard kept for safety).
    if (n < NN) {
    const int kl = lane & 31;

    ushort4 qu = *(const ushort4*)(qbh + (size_t)n * QBH_W + 4 * kl);
    float4 q4 = make_float4(bf2f(qu.x) * QSCALE, bf2f(qu.y) * QSCALE,
                            bf2f(qu.z) * QSCALE, bf2f(qu.w) * QSCALE);
    float4 sk = *(const float4*)(sb + (size_t)n * SB_W + 4 * (kl & 7));

    float s = 0.f;
    float4 acc = make_float4(0.f, 0.f, 0.f, 0.f);
    const int e0 = roff[n];
    const int cnt = roff[n + 1] - e0;
    int i = 0;
    for (; i + 4 <= cnt; i += 4) {
        int b0 = esrc[e0 + i];
        int b1 = esrc[e0 + i + 1];
        int b2 = esrc[e0 + i + 2];
        int b3 = esrc[e0 + i + 3];
        uint4 u0 = *(const uint4*)(kvb + (size_t)b0 * KV_W + 8 * kl);
        uint4 u1 = *(const uint4*)(kvb + (size_t)b1 * KV_W + 8 * kl);
        uint4 u2 = *(const uint4*)(kvb + (size_t)b2 * KV_W + 8 * kl);
        uint4 u3 = *(const uint4*)(kvb + (size_t)b3 * KV_W + 8 * kl);
        ATTN_STEP(u0); ATTN_STEP(u1); ATTN_STEP(u2); ATTN_STEP(u3);
    }
    for (; i < cnt; ++i) {
        int b0 = esrc[e0 + i];
        uint4 u0 = *(const uint4*)(kvb + (size_t)b0 * KV_W + 8 * kl);
        ATTN_STEP(u0);
    }

    float inv = (s > 0.f) ? 1.f / s : 0.f;
    float4 o;
    o.x = acc.x * inv; o.y = acc.y * inv; o.z = acc.z * inv; o.w = acc.w * inv;
    o.x += __shfl_xor(o.x, 8);  o.y += __shfl_xor(o.y, 8);  o.z += __shfl_xor(o.z, 8);  o.w += __shfl_xor(o.w, 8);
    o.x += __shfl_xor(o.x, 16); o.y += __shfl_xor(o.y, 16); o.z += __shfl_xor(o.z, 16); o.w += __shfl_xor(o.w, 16);
    if (kl < 8) {
        float4 rr;
        rr.x = fmaxf(o.x * 0.25f + sk.x, 0.f);
        rr.y = fmaxf(o.y * 0.25f + sk.y, 0.f);
        rr.z = fmaxf(o.z * 0.25f + sk.z, 0.f);
        rr.w = fmaxf(o.w * 0.25f + sk.w, 0.f);
        int c0 = 4 * kl;
        if constexpr (FINAL) {
            int slot = (tid >> 6) * 2 + hw;          // 0..7 within block
            *(float4*)(&hbuf[slot][c0]) = rr;
        } else {
            ushort4 uh = {f2h(rr.x), f2h(rr.y), f2h(rr.z), f2h(rr.w)};
            *(ushort4*)(hf + (size_t)n * HID + c0) = uh;
        }
    }
    }
    if constexpr (FINAL) {
        __syncthreads();
        if (tid < 128) {
            int slot = tid >> 4;
            int j = tid & 15;
            int n2 = blockIdx.x * 8 + slot;
            if (n2 < NN) {
                float a = bout[j];
                #pragma unroll
                for (int k = 0; k < HID; ++k)
                    a += hbuf[slot][k] * Wout[k * OUT_DIM + j];
                outp[(size_t)n2 * OUT_DIM + j] = a;
            }
        }
    }
}

extern "C" void kernel_launch(void* const* d_in, const int* in_sizes, int n_in,
                              void* d_out, int out_size, void* d_ws, size_t ws_size,
                              hipStream_t stream) {
    const float* x  = (const float*)d_in[0];
    const int*   ei = (const int*)d_in[1];
    const float* l0w[8]; const float* l1w[8];
    for (int i = 0; i < 8; ++i) { l0w[i] = (const float*)d_in[2 + i]; l1w[i] = (const float*)d_in[10 + i]; }
    const float* Wout = (const float*)d_in[18];
    const float* bout = (const float*)d_in[19];
    float* out = (float*)d_out;

    // workspace layout
    float* ws = (float*)d_ws;
    float* sb   = ws;                           // NN*32 floats
    float* bp0  = sb + (size_t)NN * SB_W;       // 416
    float* bp1  = bp0 + COLS;                   // 416
    unsigned short* qbh  = (unsigned short*)(bp1 + COLS);    // NN*128 bf16
    unsigned short* kvb  = qbh + (size_t)NN * QBH_W;         // NN*256 bf16
    unsigned short* hf   = kvb + (size_t)NN * KV_W;          // NN*32 f16
    unsigned short* Wf0  = hf + (size_t)NN * HID;            // 4*26*64*8
    unsigned short* Wf1  = Wf0 + 4 * NTILE * 64 * 8;         // 1*26*64*8
    int* ibase  = (int*)(Wf1 + NTILE * 64 * 8);
    int* roff    = ibase;                       // NN+1
    int* esrc    = roff + NN + 1;               // EE
    int* cmat    = esrc + EE;                   // NCHUNK*NBIN (~200KB)
    int* omat    = cmat + NCHUNK * NBIN;        // NCHUNK*NBIN
    int* btot    = omat + NCHUNK * NBIN;        // NBIN
    int2* pairs  = (int2*)(btot + NBIN + 2);    // EE int2 (6.4 MB)

    // merged: chunk histogram + weight pack (one launch)
    hist_pack<<<NCHUNK + PACKB, 256, 0, stream>>>(
        ei, cmat,
        l0w[0], l0w[2], l0w[4], l0w[6], l0w[1], l0w[3], l0w[5], l0w[7],
        l1w[0], l1w[2], l1w[4], l1w[6], l1w[1], l1w[3], l1w[5], l1w[7],
        Wf0, bp0, Wf1, bp1);

    // CSR: bin prefix -> scatter -> sort (bin bases recomputed locally)
    bin_prefix<<<NBIN, 256, 0, stream>>>(cmat, omat, btot);
    bin_scatter<<<NCHUNK, 256, 0, stream>>>(ei, omat, btot, pairs);
    bin_sort<<<NBIN, 256, 0, stream>>>(pairs, btot, roff, esrc);

    const int gemm_blocks = (NN + 127) / 128;    // 782
    const int attn_blocks = ((NN + 1) / 2 * 64 + 255) / 256;   // 12500 (x8 = NN)

    // layer 0: gemm reads X fp32 directly (in-staging f16 convert)
    gemm_mfma4<<<gemm_blocks, 256, 0, stream>>>(x, Wf0, bp0, qbh, sb, kvb);
    fused_attn<false><<<attn_blocks, 256, 0, stream>>>(
        qbh, sb, kvb, roff, esrc, hf, (const float*)nullptr,
        (const float*)nullptr, (float*)nullptr);

    // layer 1: gemm reads h f16 plane straight from global (no LDS)
    gemm_small<<<gemm_blocks, 256, 0, stream>>>(hf, Wf1, bp1, qbh, sb, kvb);
    fused_attn<true><<<attn_blocks, 256, 0, stream>>>(
        qbh, sb, kvb, roff, esrc, (unsigned short*)nullptr, Wout, bout, out);
}